// Round 7
// baseline (284.076 us; speedup 1.0000x reference)
//
#include <hip/hip_runtime.h>

#define NROWS 4096
#define HID 64

// ---------------- kernel 1: x=in@emb_w+b; q=x@q_w+b; kT=(x@k_w+b)^T; o pack
__global__ __launch_bounds__(64) void k_embed(
    const float* __restrict__ inp, const float* __restrict__ emb_w,
    const float* __restrict__ emb_b, const float* __restrict__ q_w,
    const float* __restrict__ q_b, const float* __restrict__ k_w,
    const float* __restrict__ k_b, float* __restrict__ q,
    float* __restrict__ kT, float* __restrict__ opk) {
  int row = blockIdx.x;
  int t = threadIdx.x;  // 64 threads
  __shared__ float in_s[8];
  __shared__ float x_s[64];
  if (t < 8) in_s[t] = inp[row * 8 + t];
  __syncthreads();
  float acc = emb_b[t];
#pragma unroll
  for (int i = 0; i < 8; ++i) acc += in_s[i] * emb_w[i * 64 + t];
  x_s[t] = acc;
  __syncthreads();
  float qa = q_b[t], ka = k_b[t];
#pragma unroll
  for (int i = 0; i < 64; ++i) {
    float xv = x_s[i];
    qa += xv * q_w[i * 64 + t];
    ka += xv * k_w[i * 64 + t];
  }
  q[row * 64 + t] = qa;
  kT[(size_t)t * NROWS + row] = ka;
  if (t < 4) opk[row * 4 + t] = inp[row * 8 + 4 + t];
}

// ---------------- kernel 2: scores + single-pass in-register softmax ------
__global__ __launch_bounds__(512, 2) void k_scores(
    const float* __restrict__ q, const float* __restrict__ kT,
    float* __restrict__ S) {
  __shared__ float4 kls[64][64];  // 64 KB
  int t = threadIdx.x;
  int w = t >> 6;
  int g = t & 63;
  int row = blockIdx.x * 8 + w;
  float qa[64];
  const float4* qp = (const float4*)(q + (size_t)row * 64);
#pragma unroll
  for (int i = 0; i < 16; ++i) {
    float4 v = qp[i];
    qa[4 * i] = v.x * 0.125f;
    qa[4 * i + 1] = v.y * 0.125f;
    qa[4 * i + 2] = v.z * 0.125f;
    qa[4 * i + 3] = v.w * 0.125f;
  }
  float4 sv[16];
#pragma unroll
  for (int tile = 0; tile < 16; ++tile) {
    __syncthreads();
#pragma unroll
    for (int it = 0; it < 8; ++it) {
      int n = it * 512 + t;
      int c = n >> 6, c4 = n & 63;
      kls[c][c4] = *(const float4*)(kT + (size_t)c * NROWS + tile * 256 + c4 * 4);
    }
    __syncthreads();
    float a0 = 0.f, a1 = 0.f, a2 = 0.f, a3 = 0.f;
#pragma unroll
    for (int c = 0; c < 64; ++c) {
      float4 kv = kls[c][g];
      a0 += qa[c] * kv.x; a1 += qa[c] * kv.y;
      a2 += qa[c] * kv.z; a3 += qa[c] * kv.w;
    }
    sv[tile] = make_float4(a0, a1, a2, a3);
  }
  float m = -1e30f;
#pragma unroll
  for (int tile = 0; tile < 16; ++tile) {
    float4 v = sv[tile];
    m = fmaxf(m, fmaxf(fmaxf(v.x, v.y), fmaxf(v.z, v.w)));
  }
#pragma unroll
  for (int off = 32; off > 0; off >>= 1) m = fmaxf(m, __shfl_xor(m, off, 64));
  float s = 0.f;
#pragma unroll
  for (int tile = 0; tile < 16; ++tile) {
    float4 v = sv[tile];
    v.x = __expf(v.x - m); v.y = __expf(v.y - m);
    v.z = __expf(v.z - m); v.w = __expf(v.w - m);
    sv[tile] = v;
    s += v.x + v.y + v.z + v.w;
  }
#pragma unroll
  for (int off = 32; off > 0; off >>= 1) s += __shfl_xor(s, off, 64);
  float li = 1.0f / s;
  float4* Sp = (float4*)(S + (size_t)row * NROWS);
#pragma unroll
  for (int tile = 0; tile < 16; ++tile) {
    float4 v = sv[tile];
    v.x *= li; v.y *= li; v.z *= li; v.w *= li;
    Sp[tile * 64 + g] = v;
  }
}

// ---------------- kernel 3: conv2 — 2 layers/pass register pyramid --------
// out tile 232x32; stage 256x52 in LDS (stride 260 dw); 5 passes x 2 layers.
// Lane l owns float4 col-group [4l..4l+3]; reads 8 cols [4l-2..4l+5]/row.
// In-place single buffer; band-boundary rows (2 bottom, 2 top per wave)
// deferred in regs and written after a barrier. Fused masked-dot epilogue.
#define OW 232
#define OH 32
#define SW 256
#define SH 52
#define SSTR 260
#define GX 18  // ceil(4096/232)

template <bool EDGE>
__device__ __forceinline__ void conv_pass(
    float* __restrict__ buf, int l, int rb, int lo_off, int gi0,
    const float* __restrict__ cmA, const float* __restrict__ cmB,
    float a10, float a1c, float a12, float a20, float a22, float aal,
    float b10, float b1c, float b12, float b20, float b22, float bal) {
  float Rm[8], Rc[8], Rp[8];
  float Am[6], Ac[6];
  float4 d0, d1, d2, d3;

#define LROW(r, R)                                            \
  {                                                           \
    const float* base_ = buf + (r) * SSTR;                    \
    float2 lo_ = *(const float2*)(base_ + lo_off);            \
    float4 mi_ = *(const float4*)(base_ + 4 * l);             \
    float2 hi_ = *(const float2*)(base_ + 4 * l + 4);         \
    R[0] = lo_.x; R[1] = lo_.y; R[2] = mi_.x; R[3] = mi_.y;   \
    R[4] = mi_.z; R[5] = mi_.w; R[6] = hi_.x; R[7] = hi_.y;   \
  }

#define EVALA(A, Vm, Vc, Vp, rowA)                                        \
  {                                                                       \
    float rm_ = 1.f;                                                      \
    if (EDGE) rm_ = ((unsigned)(gi0 + (rowA)) < (unsigned)NROWS) ? 1.f : 0.f; \
    _Pragma("unroll") for (int i_ = 0; i_ < 6; ++i_) {                    \
      int j_ = i_ + 1;                                                    \
      float h_ = a10 * Vc[j_ - 1] + a1c * Vc[j_] + a12 * Vc[j_ + 1] +     \
                 a20 * Vm[j_] + a22 * Vp[j_];                             \
      h_ = (h_ >= 0.f) ? h_ : aal * h_;                                   \
      if (EDGE) h_ *= rm_ * cmA[i_];                                      \
      A[i_] = h_;                                                         \
    }                                                                     \
  }

#define EVALB(Bv, rowB)                                                   \
  {                                                                       \
    float rm_ = 1.f;                                                      \
    if (EDGE) rm_ = ((unsigned)(gi0 + (rowB)) < (unsigned)NROWS) ? 1.f : 0.f; \
    float* bp_ = (float*)&Bv;                                             \
    _Pragma("unroll") for (int i_ = 0; i_ < 4; ++i_) {                    \
      float h_ = b10 * Ac[i_] + b1c * Ac[i_ + 1] + b12 * Ac[i_ + 2] +     \
                 b20 * Am[i_ + 1] + b22 * Ap[i_ + 1];                     \
      h_ = (h_ >= 0.f) ? h_ : bal * h_;                                   \
      if (EDGE) h_ *= rm_ * cmB[i_];                                      \
      bp_[i_] = h_;                                                       \
    }                                                                     \
  }

  // prime: A[rb-1] from rows rb-2..rb ; A[rb] from rows rb-1..rb+1
  LROW(rb - 2, Rm);
  LROW(rb - 1, Rc);
  LROW(rb, Rp);
  EVALA(Am, Rm, Rc, Rp, rb - 1);
  // shift: rows rb-1, rb in Rc,Rp; load rb+1 into Rm (reuse)
  {
    float Rn[8];
    LROW(rb + 1, Rn);
    EVALA(Ac, Rc, Rp, Rn, rb);
    // set window: Rm=cur[rb], Rc=cur[rb+1]
#pragma unroll
    for (int k = 0; k < 8; ++k) { Rm[k] = Rp[k]; Rc[k] = Rn[k]; }
  }
#pragma unroll
  for (int s = 0; s < 6; ++s) {
    int r = rb + s;
    float Ap[6];
    LROW(r + 2, Rp);            // cur[r+2]
    EVALA(Ap, Rm, Rc, Rp, r + 1);
    float4 Bv;
    EVALB(Bv, r);
    if (s == 0) d0 = Bv;
    else if (s == 1) d1 = Bv;
    else if (s == 4) d2 = Bv;
    else if (s == 5) d3 = Bv;
    else *(float4*)&buf[r * SSTR + 4 * l] = Bv;  // immediate rows rb+2, rb+3
#pragma unroll
    for (int k = 0; k < 8; ++k) { Rm[k] = Rc[k]; Rc[k] = Rp[k]; }
#pragma unroll
    for (int k = 0; k < 6; ++k) { Am[k] = Ac[k]; Ac[k] = Ap[k]; }
  }
  __syncthreads();
  *(float4*)&buf[(rb + 0) * SSTR + 4 * l] = d0;
  *(float4*)&buf[(rb + 1) * SSTR + 4 * l] = d1;
  *(float4*)&buf[(rb + 4) * SSTR + 4 * l] = d2;
  *(float4*)&buf[(rb + 5) * SSTR + 4 * l] = d3;
  __syncthreads();
#undef LROW
#undef EVALA
#undef EVALB
}

__global__ __launch_bounds__(512, 4) void k_conv2(
    const float* __restrict__ attn, float* __restrict__ partial,
    const float* __restrict__ w1p, const float* __restrict__ w2p,
    const float* __restrict__ ap, const float* __restrict__ opk) {
  __shared__ float buf[SH * SSTR];  // 52.8 KB
  int tid = threadIdx.x;
  int bx = blockIdx.x, by = blockIdx.y;
  int gi0 = by * OH - 10;
  int gj0 = bx * OW - 12;
  bool edge = (bx == 0) || (bx == GX - 1) || (by == 0) || (by == (int)gridDim.y - 1);
  // ---- stage 52 x 256 ----
  if (!edge) {
    for (int idx = tid; idx < SH * (SW / 4); idx += 512) {
      int r = idx >> 6, g = idx & 63;
      float4 v = *(const float4*)(attn + (size_t)(gi0 + r) * NROWS + gj0 + 4 * g);
      *(float4*)&buf[r * SSTR + 4 * g] = v;
    }
  } else {
    for (int idx = tid; idx < SH * (SW / 4); idx += 512) {
      int r = idx >> 6, g = idx & 63;
      int gi = gi0 + r, gj = gj0 + 4 * g;
      float4 v = {0.f, 0.f, 0.f, 0.f};
      if ((unsigned)gi < (unsigned)NROWS) {
        if (gj >= 0 && gj + 3 < NROWS) {
          v = *(const float4*)(attn + (size_t)gi * NROWS + gj);
        } else {
          float* pv = (float*)&v;
#pragma unroll
          for (int e = 0; e < 4; ++e) {
            int c = gj + e;
            if ((unsigned)c < (unsigned)NROWS) pv[e] = attn[(size_t)gi * NROWS + c];
          }
        }
      }
      *(float4*)&buf[r * SSTR + 4 * g] = v;
    }
  }
  __syncthreads();

  int wv = tid >> 6, l = tid & 63;
  int rb = 2 + 6 * wv;  // bands [2,50), h=6
  int lo_off = (l == 0) ? 0 : 4 * l - 2;
  float cmA[6], cmB[4];
  if (edge) {
#pragma unroll
    for (int i = 0; i < 6; ++i) {
      int gc = gj0 + 4 * l - 1 + i;
      cmA[i] = ((unsigned)gc < (unsigned)NROWS) ? 1.f : 0.f;
    }
#pragma unroll
    for (int i = 0; i < 4; ++i) {
      int gc = gj0 + 4 * l + i;
      cmB[i] = ((unsigned)gc < (unsigned)NROWS) ? 1.f : 0.f;
    }
  }

  for (int p = 0; p < 5; ++p) {
    int lA = 2 * p, lB = 2 * p + 1;
    float a10 = w1p[3 * lA], a12 = w1p[3 * lA + 2];
    float a1c = w1p[3 * lA + 1] + w2p[3 * lA + 1];
    float a20 = w2p[3 * lA], a22 = w2p[3 * lA + 2];
    float aal = ap[lA];
    float b10 = w1p[3 * lB], b12 = w1p[3 * lB + 2];
    float b1c = w1p[3 * lB + 1] + w2p[3 * lB + 1];
    float b20 = w2p[3 * lB], b22 = w2p[3 * lB + 2];
    float bal = ap[lB];
    if (edge)
      conv_pass<true>(buf, l, rb, lo_off, gi0, cmA, cmB, a10, a1c, a12, a20,
                      a22, aal, b10, b1c, b12, b20, b22, bal);
    else
      conv_pass<false>(buf, l, rb, lo_off, gi0, cmA, cmB, a10, a1c, a12, a20,
                       a22, aal, b10, b1c, b12, b20, b22, bal);
  }

  // ---- epilogue: masked dot over inner 232x32 (rows [10,42), cols [12,244))
  int i = tid >> 4;    // 0..31
  int part = tid & 15;
  int gi = gi0 + 10 + i;
  float a0 = 0.f, a1 = 0.f, a2 = 0.f, a3 = 0.f;
  for (int g = part; g < OW / 4; g += 16) {
    int jc = 12 + 4 * g;
    int gj = gj0 + jc;  // = bx*OW + 4*g
    if (gj < NROWS) {
      float4 cf = *(float4*)&buf[(10 + i) * SSTR + jc];
      float4 av = *(const float4*)(attn + (size_t)gi * NROWS + gj);
      const float4* op = (const float4*)opk;
      if (cf.x > 0.f) { float4 o = op[gj + 0]; a0 += av.x * o.x; a1 += av.x * o.y; a2 += av.x * o.z; a3 += av.x * o.w; }
      if (cf.y > 0.f) { float4 o = op[gj + 1]; a0 += av.y * o.x; a1 += av.y * o.y; a2 += av.y * o.z; a3 += av.y * o.w; }
      if (cf.z > 0.f) { float4 o = op[gj + 2]; a0 += av.z * o.x; a1 += av.z * o.y; a2 += av.z * o.z; a3 += av.z * o.w; }
      if (cf.w > 0.f) { float4 o = op[gj + 3]; a0 += av.w * o.x; a1 += av.w * o.y; a2 += av.w * o.z; a3 += av.w * o.w; }
    }
  }
#pragma unroll
  for (int off = 1; off < 16; off <<= 1) {
    a0 += __shfl_xor(a0, off, 64);
    a1 += __shfl_xor(a1, off, 64);
    a2 += __shfl_xor(a2, off, 64);
    a3 += __shfl_xor(a3, off, 64);
  }
  if (part == 0) {
    float4 r = {a0, a1, a2, a3};
    *(float4*)&partial[((size_t)bx * NROWS + gi) * 4] = r;
  }
}

// ---------------- kernel 4: reduce 18 partials + gcn + mlp head -----------
__global__ __launch_bounds__(64) void k_head(
    const float* __restrict__ partial, const float* __restrict__ gcn_w,
    const float* __restrict__ gcn_b, const float* __restrict__ gcn_a,
    const float* __restrict__ w1, const float* __restrict__ b1,
    const float* __restrict__ w2, const float* __restrict__ b2,
    float* __restrict__ out) {
  int row = blockIdx.x;
  int t = threadIdx.x;  // 64
  __shared__ float c4[4];
  __shared__ float gs[64];
  __shared__ float ms[32];
  {
    int c = t & 3, gg = t >> 2;  // gg in [0,16)
    float s = partial[((size_t)gg * NROWS + row) * 4 + c];
    if (gg < GX - 16)
      s += partial[((size_t)(gg + 16) * NROWS + row) * 4 + c];
#pragma unroll
    for (int off = 4; off < 64; off <<= 1) s += __shfl_xor(s, off, 64);
    if (t < 4) c4[t] = s;
  }
  __syncthreads();
  float g = gcn_b[t];
#pragma unroll
  for (int d = 0; d < 4; ++d) g += c4[d] * gcn_w[d * 64 + t];
  float ga = gcn_a[0];
  gs[t] = (g >= 0.f) ? g : ga * g;
  __syncthreads();
  if (t < 32) {
    float mm = b1[t];
#pragma unroll
    for (int i = 0; i < 64; ++i) mm += gs[i] * w1[i * 32 + t];
    ms[t] = fmaxf(mm, 0.f);
  }
  __syncthreads();
  if (t < 4) {
    float o = b2[t];
#pragma unroll
    for (int i = 0; i < 32; ++i) o += ms[i] * w2[i * 4 + t];
    out[row * 4 + t] = o;
  }
}

extern "C" void kernel_launch(void* const* d_in, const int* in_sizes, int n_in,
                              void* d_out, int out_size, void* d_ws, size_t ws_size,
                              hipStream_t stream) {
  (void)in_sizes; (void)n_in; (void)out_size; (void)ws_size;
  const float* inp    = (const float*)d_in[0];
  const float* emb_w  = (const float*)d_in[1];
  const float* emb_b  = (const float*)d_in[2];
  const float* q_w    = (const float*)d_in[3];
  const float* q_b    = (const float*)d_in[4];
  const float* k_w    = (const float*)d_in[5];
  const float* k_b    = (const float*)d_in[6];
  const float* conv_w1 = (const float*)d_in[7];
  const float* conv_w2 = (const float*)d_in[8];
  const float* conv_a  = (const float*)d_in[9];
  const float* gcn_w  = (const float*)d_in[10];
  const float* gcn_b  = (const float*)d_in[11];
  const float* gcn_a  = (const float*)d_in[12];
  const float* mlp_w1 = (const float*)d_in[13];
  const float* mlp_b1 = (const float*)d_in[14];
  const float* mlp_w2 = (const float*)d_in[15];
  const float* mlp_b2 = (const float*)d_in[16];
  float* out = (float*)d_out;

  const size_t NN = (size_t)NROWS * NROWS;
  float* A       = (float*)d_ws;                      // 4096^2 attn
  float* partial = A + NN;                            // GX * 4096 * 4
  float* q       = partial + (size_t)GX * NROWS * 4;
  float* kT      = q + (size_t)NROWS * HID;
  float* opk     = kT + (size_t)NROWS * HID;          // 4096*4

  k_embed<<<NROWS, 64, 0, stream>>>(inp, emb_w, emb_b, q_w, q_b, k_w, k_b, q, kT, opk);
  k_scores<<<NROWS / 8, 512, 0, stream>>>(q, kT, A);
  k_conv2<<<dim3(GX, NROWS / OH), 512, 0, stream>>>(A, partial, conv_w1,
                                                    conv_w2, conv_a, opk);
  k_head<<<NROWS, 64, 0, stream>>>(partial, gcn_w, gcn_b, gcn_a, mlp_w1, mlp_b1,
                                   mlp_w2, mlp_b2, out);
}

// Round 8
// 276.473 us; speedup vs baseline: 1.0275x; 1.0275x over previous
//
#include <hip/hip_runtime.h>

#define NROWS 4096
#define HID 64

// ---------------- kernel 1: x=in@emb_w+b; q=x@q_w+b; kT=(x@k_w+b)^T; o pack
__global__ __launch_bounds__(64) void k_embed(
    const float* __restrict__ inp, const float* __restrict__ emb_w,
    const float* __restrict__ emb_b, const float* __restrict__ q_w,
    const float* __restrict__ q_b, const float* __restrict__ k_w,
    const float* __restrict__ k_b, float* __restrict__ q,
    float* __restrict__ kT, float* __restrict__ opk) {
  int row = blockIdx.x;
  int t = threadIdx.x;  // 64 threads
  __shared__ float in_s[8];
  __shared__ float x_s[64];
  if (t < 8) in_s[t] = inp[row * 8 + t];
  __syncthreads();
  float acc = emb_b[t];
#pragma unroll
  for (int i = 0; i < 8; ++i) acc += in_s[i] * emb_w[i * 64 + t];
  x_s[t] = acc;
  __syncthreads();
  float qa = q_b[t], ka = k_b[t];
#pragma unroll
  for (int i = 0; i < 64; ++i) {
    float xv = x_s[i];
    qa += xv * q_w[i * 64 + t];
    ka += xv * k_w[i * 64 + t];
  }
  q[row * 64 + t] = qa;
  kT[(size_t)t * NROWS + row] = ka;
  if (t < 4) opk[row * 4 + t] = inp[row * 8 + 4 + t];
}

// ---------------- kernel 2: scores + single-pass in-register softmax ------
__global__ __launch_bounds__(512, 2) void k_scores(
    const float* __restrict__ q, const float* __restrict__ kT,
    float* __restrict__ S) {
  __shared__ float4 kls[64][64];  // 64 KB
  int t = threadIdx.x;
  int w = t >> 6;
  int g = t & 63;
  int row = blockIdx.x * 8 + w;
  float qa[64];
  const float4* qp = (const float4*)(q + (size_t)row * 64);
#pragma unroll
  for (int i = 0; i < 16; ++i) {
    float4 v = qp[i];
    qa[4 * i] = v.x * 0.125f;
    qa[4 * i + 1] = v.y * 0.125f;
    qa[4 * i + 2] = v.z * 0.125f;
    qa[4 * i + 3] = v.w * 0.125f;
  }
  float4 sv[16];
#pragma unroll
  for (int tile = 0; tile < 16; ++tile) {
    __syncthreads();
#pragma unroll
    for (int it = 0; it < 8; ++it) {
      int n = it * 512 + t;
      int c = n >> 6, c4 = n & 63;
      kls[c][c4] = *(const float4*)(kT + (size_t)c * NROWS + tile * 256 + c4 * 4);
    }
    __syncthreads();
    float a0 = 0.f, a1 = 0.f, a2 = 0.f, a3 = 0.f;
#pragma unroll
    for (int c = 0; c < 64; ++c) {
      float4 kv = kls[c][g];
      a0 += qa[c] * kv.x; a1 += qa[c] * kv.y;
      a2 += qa[c] * kv.z; a3 += qa[c] * kv.w;
    }
    sv[tile] = make_float4(a0, a1, a2, a3);
  }
  float m = -1e30f;
#pragma unroll
  for (int tile = 0; tile < 16; ++tile) {
    float4 v = sv[tile];
    m = fmaxf(m, fmaxf(fmaxf(v.x, v.y), fmaxf(v.z, v.w)));
  }
#pragma unroll
  for (int off = 32; off > 0; off >>= 1) m = fmaxf(m, __shfl_xor(m, off, 64));
  float s = 0.f;
#pragma unroll
  for (int tile = 0; tile < 16; ++tile) {
    float4 v = sv[tile];
    v.x = __expf(v.x - m); v.y = __expf(v.y - m);
    v.z = __expf(v.z - m); v.w = __expf(v.w - m);
    sv[tile] = v;
    s += v.x + v.y + v.z + v.w;
  }
#pragma unroll
  for (int off = 32; off > 0; off >>= 1) s += __shfl_xor(s, off, 64);
  float li = 1.0f / s;
  float4* Sp = (float4*)(S + (size_t)row * NROWS);
#pragma unroll
  for (int tile = 0; tile < 16; ++tile) {
    float4 v = sv[tile];
    v.x *= li; v.y *= li; v.z *= li; v.w *= li;
    Sp[tile * 64 + g] = v;
  }
}

// ---------------- kernel 3: conv2 — 2 layers/pass register pyramid --------
// out tile 232x32; stage 256x52 in LDS (stride 260 dw); 5 passes x 2 layers.
// Lane l owns float4 col-group [4l..4l+3]; per row 3 ALIGNED b128 reads at
// 4l-4 / 4l / 4l+4 (conflict-free lane-stride-16B pattern; no b64, no shfl).
// In-place single buffer; band-boundary rows deferred in regs, written after
// a barrier. Fused masked-dot epilogue (conv never touches HBM).
#define OW 232
#define OH 32
#define SW 256
#define SH 52
#define SSTR 260
#define GX 18  // ceil(4096/232)

template <bool EDGE>
__device__ __forceinline__ void conv_pass(
    float* __restrict__ buf, int l, int rb, int lo_off, int gi0,
    const float* __restrict__ cmA, const float* __restrict__ cmB,
    float a10, float a1c, float a12, float a20, float a22, float aal,
    float b10, float b1c, float b12, float b20, float b22, float bal) {
  float Rm[8], Rc[8], Rp[8];
  float Am[6], Ac[6];
  float4 d0, d1, d2, d3;

  // window R[0..7] = cur row cols [4l-2 .. 4l+5], via 3 aligned float4 loads
#define LROW(r, R)                                            \
  {                                                           \
    const float* base_ = buf + (r) * SSTR;                    \
    float4 lo_ = *(const float4*)(base_ + lo_off);            \
    float4 mi_ = *(const float4*)(base_ + 4 * l);             \
    float4 hi_ = *(const float4*)(base_ + 4 * l + 4);         \
    R[0] = lo_.z; R[1] = lo_.w; R[2] = mi_.x; R[3] = mi_.y;   \
    R[4] = mi_.z; R[5] = mi_.w; R[6] = hi_.x; R[7] = hi_.y;   \
  }

#define EVALA(A, Vm, Vc, Vp, rowA)                                        \
  {                                                                       \
    float rm_ = 1.f;                                                      \
    if (EDGE) rm_ = ((unsigned)(gi0 + (rowA)) < (unsigned)NROWS) ? 1.f : 0.f; \
    _Pragma("unroll") for (int i_ = 0; i_ < 6; ++i_) {                    \
      int j_ = i_ + 1;                                                    \
      float h_ = a10 * Vc[j_ - 1] + a1c * Vc[j_] + a12 * Vc[j_ + 1] +     \
                 a20 * Vm[j_] + a22 * Vp[j_];                             \
      h_ = (h_ >= 0.f) ? h_ : aal * h_;                                   \
      if (EDGE) h_ *= rm_ * cmA[i_];                                      \
      A[i_] = h_;                                                         \
    }                                                                     \
  }

#define EVALB(Bv, rowB)                                                   \
  {                                                                       \
    float rm_ = 1.f;                                                      \
    if (EDGE) rm_ = ((unsigned)(gi0 + (rowB)) < (unsigned)NROWS) ? 1.f : 0.f; \
    float* bp_ = (float*)&Bv;                                             \
    _Pragma("unroll") for (int i_ = 0; i_ < 4; ++i_) {                    \
      float h_ = b10 * Ac[i_] + b1c * Ac[i_ + 1] + b12 * Ac[i_ + 2] +     \
                 b20 * Am[i_ + 1] + b22 * Ap[i_ + 1];                     \
      h_ = (h_ >= 0.f) ? h_ : bal * h_;                                   \
      if (EDGE) h_ *= rm_ * cmB[i_];                                      \
      bp_[i_] = h_;                                                       \
    }                                                                     \
  }

  // prime: A[rb-1] from rows rb-2..rb ; A[rb] from rows rb-1..rb+1
  LROW(rb - 2, Rm);
  LROW(rb - 1, Rc);
  LROW(rb, Rp);
  EVALA(Am, Rm, Rc, Rp, rb - 1);
  {
    float Rn[8];
    LROW(rb + 1, Rn);
    EVALA(Ac, Rc, Rp, Rn, rb);
#pragma unroll
    for (int k = 0; k < 8; ++k) { Rm[k] = Rp[k]; Rc[k] = Rn[k]; }
  }
#pragma unroll
  for (int s = 0; s < 6; ++s) {
    int r = rb + s;
    float Ap[6];
    LROW(r + 2, Rp);            // cur[r+2]
    EVALA(Ap, Rm, Rc, Rp, r + 1);
    float4 Bv;
    EVALB(Bv, r);
    if (s == 0) d0 = Bv;
    else if (s == 1) d1 = Bv;
    else if (s == 4) d2 = Bv;
    else if (s == 5) d3 = Bv;
    else *(float4*)&buf[r * SSTR + 4 * l] = Bv;  // immediate rows rb+2, rb+3
#pragma unroll
    for (int k = 0; k < 8; ++k) { Rm[k] = Rc[k]; Rc[k] = Rp[k]; }
#pragma unroll
    for (int k = 0; k < 6; ++k) { Am[k] = Ac[k]; Ac[k] = Ap[k]; }
  }
  __syncthreads();
  *(float4*)&buf[(rb + 0) * SSTR + 4 * l] = d0;
  *(float4*)&buf[(rb + 1) * SSTR + 4 * l] = d1;
  *(float4*)&buf[(rb + 4) * SSTR + 4 * l] = d2;
  *(float4*)&buf[(rb + 5) * SSTR + 4 * l] = d3;
  __syncthreads();
#undef LROW
#undef EVALA
#undef EVALB
}

__global__ __launch_bounds__(512, 2) void k_conv2(
    const float* __restrict__ attn, float* __restrict__ partial,
    const float* __restrict__ w1p, const float* __restrict__ w2p,
    const float* __restrict__ ap, const float* __restrict__ opk) {
  __shared__ float buf[SH * SSTR];  // 52.8 KB
  int tid = threadIdx.x;
  int bx = blockIdx.x, by = blockIdx.y;
  int gi0 = by * OH - 10;
  int gj0 = bx * OW - 12;
  bool edge = (bx == 0) || (bx == GX - 1) || (by == 0) || (by == (int)gridDim.y - 1);
  // ---- stage 52 x 256 ----
  if (!edge) {
    for (int idx = tid; idx < SH * (SW / 4); idx += 512) {
      int r = idx >> 6, g = idx & 63;
      float4 v = *(const float4*)(attn + (size_t)(gi0 + r) * NROWS + gj0 + 4 * g);
      *(float4*)&buf[r * SSTR + 4 * g] = v;
    }
  } else {
    for (int idx = tid; idx < SH * (SW / 4); idx += 512) {
      int r = idx >> 6, g = idx & 63;
      int gi = gi0 + r, gj = gj0 + 4 * g;
      float4 v = {0.f, 0.f, 0.f, 0.f};
      if ((unsigned)gi < (unsigned)NROWS) {
        if (gj >= 0 && gj + 3 < NROWS) {
          v = *(const float4*)(attn + (size_t)gi * NROWS + gj);
        } else {
          float* pv = (float*)&v;
#pragma unroll
          for (int e = 0; e < 4; ++e) {
            int c = gj + e;
            if ((unsigned)c < (unsigned)NROWS) pv[e] = attn[(size_t)gi * NROWS + c];
          }
        }
      }
      *(float4*)&buf[r * SSTR + 4 * g] = v;
    }
  }
  __syncthreads();

  int wv = tid >> 6, l = tid & 63;
  int rb = 2 + 6 * wv;  // bands [2,50), h=6
  int lo_off = (l == 0) ? 0 : 4 * l - 4;
  float cmA[6], cmB[4];
  if (edge) {
#pragma unroll
    for (int i = 0; i < 6; ++i) {
      int gc = gj0 + 4 * l - 1 + i;
      cmA[i] = ((unsigned)gc < (unsigned)NROWS) ? 1.f : 0.f;
    }
#pragma unroll
    for (int i = 0; i < 4; ++i) {
      int gc = gj0 + 4 * l + i;
      cmB[i] = ((unsigned)gc < (unsigned)NROWS) ? 1.f : 0.f;
    }
  }

  for (int p = 0; p < 5; ++p) {
    int lA = 2 * p, lB = 2 * p + 1;
    float a10 = w1p[3 * lA], a12 = w1p[3 * lA + 2];
    float a1c = w1p[3 * lA + 1] + w2p[3 * lA + 1];
    float a20 = w2p[3 * lA], a22 = w2p[3 * lA + 2];
    float aal = ap[lA];
    float b10 = w1p[3 * lB], b12 = w1p[3 * lB + 2];
    float b1c = w1p[3 * lB + 1] + w2p[3 * lB + 1];
    float b20 = w2p[3 * lB], b22 = w2p[3 * lB + 2];
    float bal = ap[lB];
    if (edge)
      conv_pass<true>(buf, l, rb, lo_off, gi0, cmA, cmB, a10, a1c, a12, a20,
                      a22, aal, b10, b1c, b12, b20, b22, bal);
    else
      conv_pass<false>(buf, l, rb, lo_off, gi0, cmA, cmB, a10, a1c, a12, a20,
                       a22, aal, b10, b1c, b12, b20, b22, bal);
  }

  // ---- epilogue: masked dot over inner 232x32 (rows [10,42), cols [12,244))
  int i = tid >> 4;    // 0..31
  int part = tid & 15;
  int gi = gi0 + 10 + i;
  float a0 = 0.f, a1 = 0.f, a2 = 0.f, a3 = 0.f;
  for (int g = part; g < OW / 4; g += 16) {
    int jc = 12 + 4 * g;
    int gj = gj0 + jc;  // = bx*OW + 4*g
    if (gj < NROWS) {
      float4 cf = *(float4*)&buf[(10 + i) * SSTR + jc];
      float4 av = *(const float4*)(attn + (size_t)gi * NROWS + gj);
      const float4* op = (const float4*)opk;
      if (cf.x > 0.f) { float4 o = op[gj + 0]; a0 += av.x * o.x; a1 += av.x * o.y; a2 += av.x * o.z; a3 += av.x * o.w; }
      if (cf.y > 0.f) { float4 o = op[gj + 1]; a0 += av.y * o.x; a1 += av.y * o.y; a2 += av.y * o.z; a3 += av.y * o.w; }
      if (cf.z > 0.f) { float4 o = op[gj + 2]; a0 += av.z * o.x; a1 += av.z * o.y; a2 += av.z * o.z; a3 += av.z * o.w; }
      if (cf.w > 0.f) { float4 o = op[gj + 3]; a0 += av.w * o.x; a1 += av.w * o.y; a2 += av.w * o.z; a3 += av.w * o.w; }
    }
  }
#pragma unroll
  for (int off = 1; off < 16; off <<= 1) {
    a0 += __shfl_xor(a0, off, 64);
    a1 += __shfl_xor(a1, off, 64);
    a2 += __shfl_xor(a2, off, 64);
    a3 += __shfl_xor(a3, off, 64);
  }
  if (part == 0) {
    float4 r = {a0, a1, a2, a3};
    *(float4*)&partial[((size_t)bx * NROWS + gi) * 4] = r;
  }
}

// ---------------- kernel 4: reduce 18 partials + gcn + mlp head -----------
__global__ __launch_bounds__(64) void k_head(
    const float* __restrict__ partial, const float* __restrict__ gcn_w,
    const float* __restrict__ gcn_b, const float* __restrict__ gcn_a,
    const float* __restrict__ w1, const float* __restrict__ b1,
    const float* __restrict__ w2, const float* __restrict__ b2,
    float* __restrict__ out) {
  int row = blockIdx.x;
  int t = threadIdx.x;  // 64
  __shared__ float c4[4];
  __shared__ float gs[64];
  __shared__ float ms[32];
  {
    int c = t & 3, gg = t >> 2;  // gg in [0,16)
    float s = partial[((size_t)gg * NROWS + row) * 4 + c];
    if (gg < GX - 16)
      s += partial[((size_t)(gg + 16) * NROWS + row) * 4 + c];
#pragma unroll
    for (int off = 4; off < 64; off <<= 1) s += __shfl_xor(s, off, 64);
    if (t < 4) c4[t] = s;
  }
  __syncthreads();
  float g = gcn_b[t];
#pragma unroll
  for (int d = 0; d < 4; ++d) g += c4[d] * gcn_w[d * 64 + t];
  float ga = gcn_a[0];
  gs[t] = (g >= 0.f) ? g : ga * g;
  __syncthreads();
  if (t < 32) {
    float mm = b1[t];
#pragma unroll
    for (int i = 0; i < 64; ++i) mm += gs[i] * w1[i * 32 + t];
    ms[t] = fmaxf(mm, 0.f);
  }
  __syncthreads();
  if (t < 4) {
    float o = b2[t];
#pragma unroll
    for (int i = 0; i < 32; ++i) o += ms[i] * w2[i * 4 + t];
    out[row * 4 + t] = o;
  }
}

extern "C" void kernel_launch(void* const* d_in, const int* in_sizes, int n_in,
                              void* d_out, int out_size, void* d_ws, size_t ws_size,
                              hipStream_t stream) {
  (void)in_sizes; (void)n_in; (void)out_size; (void)ws_size;
  const float* inp    = (const float*)d_in[0];
  const float* emb_w  = (const float*)d_in[1];
  const float* emb_b  = (const float*)d_in[2];
  const float* q_w    = (const float*)d_in[3];
  const float* q_b    = (const float*)d_in[4];
  const float* k_w    = (const float*)d_in[5];
  const float* k_b    = (const float*)d_in[6];
  const float* conv_w1 = (const float*)d_in[7];
  const float* conv_w2 = (const float*)d_in[8];
  const float* conv_a  = (const float*)d_in[9];
  const float* gcn_w  = (const float*)d_in[10];
  const float* gcn_b  = (const float*)d_in[11];
  const float* gcn_a  = (const float*)d_in[12];
  const float* mlp_w1 = (const float*)d_in[13];
  const float* mlp_b1 = (const float*)d_in[14];
  const float* mlp_w2 = (const float*)d_in[15];
  const float* mlp_b2 = (const float*)d_in[16];
  float* out = (float*)d_out;

  const size_t NN = (size_t)NROWS * NROWS;
  float* A       = (float*)d_ws;                      // 4096^2 attn
  float* partial = A + NN;                            // GX * 4096 * 4
  float* q       = partial + (size_t)GX * NROWS * 4;
  float* kT      = q + (size_t)NROWS * HID;
  float* opk     = kT + (size_t)NROWS * HID;          // 4096*4

  k_embed<<<NROWS, 64, 0, stream>>>(inp, emb_w, emb_b, q_w, q_b, k_w, k_b, q, kT, opk);
  k_scores<<<NROWS / 8, 512, 0, stream>>>(q, kT, A);
  k_conv2<<<dim3(GX, NROWS / OH), 512, 0, stream>>>(A, partial, conv_w1,
                                                    conv_w2, conv_a, opk);
  k_head<<<NROWS, 64, 0, stream>>>(partial, gcn_w, gcn_b, gcn_a, mlp_w1, mlp_b1,
                                   mlp_w2, mlp_b2, out);
}

// Round 10
// 190.412 us; speedup vs baseline: 1.4919x; 1.4520x over previous
//
#include <hip/hip_runtime.h>
#include <hip/hip_fp16.h>

#define NROWS 4096
#define HID 64

static __device__ __forceinline__ __half2 u2h(unsigned u) {
  __half2 h; __builtin_memcpy(&h, &u, 4); return h;
}
static __device__ __forceinline__ unsigned h2u(__half2 h) {
  unsigned u; __builtin_memcpy(&u, &h, 4); return u;
}

// ---------------- kernel 1: x=in@emb_w+b; q=x@q_w+b; kT=(x@k_w+b)^T; o pack
__global__ __launch_bounds__(64) void k_embed(
    const float* __restrict__ inp, const float* __restrict__ emb_w,
    const float* __restrict__ emb_b, const float* __restrict__ q_w,
    const float* __restrict__ q_b, const float* __restrict__ k_w,
    const float* __restrict__ k_b, float* __restrict__ q,
    float* __restrict__ kT, float* __restrict__ opk) {
  int row = blockIdx.x;
  int t = threadIdx.x;  // 64 threads
  __shared__ float in_s[8];
  __shared__ float x_s[64];
  if (t < 8) in_s[t] = inp[row * 8 + t];
  __syncthreads();
  float acc = emb_b[t];
#pragma unroll
  for (int i = 0; i < 8; ++i) acc += in_s[i] * emb_w[i * 64 + t];
  x_s[t] = acc;
  __syncthreads();
  float qa = q_b[t], ka = k_b[t];
#pragma unroll
  for (int i = 0; i < 64; ++i) {
    float xv = x_s[i];
    qa += xv * q_w[i * 64 + t];
    ka += xv * k_w[i * 64 + t];
  }
  q[row * 64 + t] = qa;
  kT[(size_t)t * NROWS + row] = ka;
  if (t < 4) opk[row * 4 + t] = inp[row * 8 + 4 + t];
}

// ---------------- kernel 2: scores + single-pass in-register softmax ------
__global__ __launch_bounds__(512, 2) void k_scores(
    const float* __restrict__ q, const float* __restrict__ kT,
    float* __restrict__ S) {
  __shared__ float4 kls[64][64];  // 64 KB
  int t = threadIdx.x;
  int w = t >> 6;
  int g = t & 63;
  int row = blockIdx.x * 8 + w;
  float qa[64];
  const float4* qp = (const float4*)(q + (size_t)row * 64);
#pragma unroll
  for (int i = 0; i < 16; ++i) {
    float4 v = qp[i];
    qa[4 * i] = v.x * 0.125f;
    qa[4 * i + 1] = v.y * 0.125f;
    qa[4 * i + 2] = v.z * 0.125f;
    qa[4 * i + 3] = v.w * 0.125f;
  }
  float4 sv[16];
#pragma unroll
  for (int tile = 0; tile < 16; ++tile) {
    __syncthreads();
#pragma unroll
    for (int it = 0; it < 8; ++it) {
      int n = it * 512 + t;
      int c = n >> 6, c4 = n & 63;
      kls[c][c4] = *(const float4*)(kT + (size_t)c * NROWS + tile * 256 + c4 * 4);
    }
    __syncthreads();
    float a0 = 0.f, a1 = 0.f, a2 = 0.f, a3 = 0.f;
#pragma unroll
    for (int c = 0; c < 64; ++c) {
      float4 kv = kls[c][g];
      a0 += qa[c] * kv.x; a1 += qa[c] * kv.y;
      a2 += qa[c] * kv.z; a3 += qa[c] * kv.w;
    }
    sv[tile] = make_float4(a0, a1, a2, a3);
  }
  float m = -1e30f;
#pragma unroll
  for (int tile = 0; tile < 16; ++tile) {
    float4 v = sv[tile];
    m = fmaxf(m, fmaxf(fmaxf(v.x, v.y), fmaxf(v.z, v.w)));
  }
#pragma unroll
  for (int off = 32; off > 0; off >>= 1) m = fmaxf(m, __shfl_xor(m, off, 64));
  float s = 0.f;
#pragma unroll
  for (int tile = 0; tile < 16; ++tile) {
    float4 v = sv[tile];
    v.x = __expf(v.x - m); v.y = __expf(v.y - m);
    v.z = __expf(v.z - m); v.w = __expf(v.w - m);
    sv[tile] = v;
    s += v.x + v.y + v.z + v.w;
  }
#pragma unroll
  for (int off = 32; off > 0; off >>= 1) s += __shfl_xor(s, off, 64);
  float li = 1.0f / s;
  float4* Sp = (float4*)(S + (size_t)row * NROWS);
#pragma unroll
  for (int tile = 0; tile < 16; ++tile) {
    float4 v = sv[tile];
    v.x *= li; v.y *= li; v.z *= li; v.w *= li;
    Sp[tile * 64 + g] = v;
  }
}

// ---------------- kernel 3: conv3 — packed fp16, 1 layer/pass, dbuf -------
// Stage 256 fp16 cols x 50 rows (x256 scale; conv is positively homogeneous
// so mask sign is invariant). Lane owns 4 cols = 2 packed dwords; horizontal
// halo via DPP wave_shr/shl (VALU pipe); 1 b64 read + 1 b64 write per row.
// Leaky-relu via sign-bit bit-select (no __hmax2 on ROCm 7.2).
// Ping-pong buffers, 1 barrier/layer. Valid region shrinks 1/pass; interior
// [10,40)x[10,246) clean after 10. Fused masked-dot epilogue.
#define SWH 128    // dwords per data row (256 fp16)
#define SHH 50
#define SSTRH 130  // dword stride (8B aligned rows)
#define OWW 236
#define OHH 30
#define GX 18      // ceil(4096/236)
#define GY 137     // ceil(4096/30)

__global__ __launch_bounds__(512, 2) void k_conv3(
    const float* __restrict__ attn, float* __restrict__ partial,
    const float* __restrict__ w1p, const float* __restrict__ w2p,
    const float* __restrict__ ap, const float* __restrict__ opk) {
  __shared__ unsigned buf[2][SHH * SSTRH];  // 2 x 26 KB
  int tid = threadIdx.x;
  int bx = blockIdx.x, by = blockIdx.y;
  int gi0 = by * OHH - 10;
  int gj0 = bx * OWW - 10;
  bool edge = (bx == 0) || (bx == GX - 1) || (by == 0) || (by == GY - 1);
  // ---- stage: fp32 -> fp16 x256 ----
  if (!edge) {
    for (int idx = tid; idx < SHH * SWH; idx += 512) {
      int r = idx >> 7, d = idx & 127;
      float2 v = *(const float2*)(attn + (size_t)(gi0 + r) * NROWS + gj0 + 2 * d);
      buf[0][r * SSTRH + d] =
          h2u(__float22half2_rn(make_float2(v.x * 256.f, v.y * 256.f)));
    }
  } else {
    for (int idx = tid; idx < SHH * SWH; idx += 512) {
      int r = idx >> 7, d = idx & 127;
      int gi = gi0 + r, gj = gj0 + 2 * d;
      float a = 0.f, b = 0.f;
      if ((unsigned)gi < (unsigned)NROWS) {
        if ((unsigned)gj < (unsigned)NROWS) a = attn[(size_t)gi * NROWS + gj] * 256.f;
        if ((unsigned)(gj + 1) < (unsigned)NROWS) b = attn[(size_t)gi * NROWS + gj + 1] * 256.f;
      }
      buf[0][r * SSTRH + d] = h2u(__float22half2_rn(make_float2(a, b)));
    }
  }
  __syncthreads();

  int wv = tid >> 6, l = tid & 63;
  int rb = 1 + 6 * wv;   // 8 waves x 6 rows = rows [1,49)
  int doff = 2 * l;      // dword offset within row (cols 4l..4l+3)
  __half2 CM0 = __float2half2_rn(1.f), CM1 = __float2half2_rn(1.f);
  if (edge) {
    float m0 = ((unsigned)(gj0 + 4 * l + 0) < (unsigned)NROWS) ? 1.f : 0.f;
    float m1 = ((unsigned)(gj0 + 4 * l + 1) < (unsigned)NROWS) ? 1.f : 0.f;
    float m2 = ((unsigned)(gj0 + 4 * l + 2) < (unsigned)NROWS) ? 1.f : 0.f;
    float m3 = ((unsigned)(gj0 + 4 * l + 3) < (unsigned)NROWS) ? 1.f : 0.f;
    CM0 = __float22half2_rn(make_float2(m0, m1));
    CM1 = __float22half2_rn(make_float2(m2, m3));
  }

  for (int p = 0; p < 10; ++p) {
    unsigned* src = buf[p & 1];
    unsigned* dst = buf[(p + 1) & 1];
    __half2 W10 = __float2half2_rn(w1p[3 * p]);
    __half2 W12 = __float2half2_rn(w1p[3 * p + 2]);
    __half2 WC  = __float2half2_rn(w1p[3 * p + 1] + w2p[3 * p + 1]);
    __half2 W20 = __float2half2_rn(w2p[3 * p]);
    __half2 W22 = __float2half2_rn(w2p[3 * p + 2]);
    __half2 AL  = __float2half2_rn(ap[p]);
    uint2 Vm = *(uint2*)&src[(rb - 1) * SSTRH + doff];
    uint2 Vc = *(uint2*)&src[rb * SSTRH + doff];
#pragma unroll
    for (int s = 0; s < 6; ++s) {
      int r = rb + s;
      uint2 Vp = *(uint2*)&src[(r + 1) * SSTRH + doff];
      // horizontal halo from neighbor lanes (VALU pipe, zero-fill edges)
      unsigned Lm1 = (unsigned)__builtin_amdgcn_update_dpp(
          0, (int)Vc.y, 0x138, 0xF, 0xF, true);  // wave_shr1: lane l-1's P1
      unsigned Hp1 = (unsigned)__builtin_amdgcn_update_dpp(
          0, (int)Vc.x, 0x130, 0xF, 0xF, true);  // wave_shl1: lane l+1's P0
      unsigned SL0 = __builtin_amdgcn_alignbit(Vc.x, Lm1, 16);  // (c-1,c0)
      unsigned SR0 = __builtin_amdgcn_alignbit(Vc.y, Vc.x, 16); // (c1,c2)
      unsigned SR1 = __builtin_amdgcn_alignbit(Hp1, Vc.y, 16);  // (c3,c4)
      __half2 o0 = __hmul2(WC, u2h(Vc.x));
      o0 = __hfma2(W10, u2h(SL0), o0);
      o0 = __hfma2(W12, u2h(SR0), o0);
      o0 = __hfma2(W20, u2h(Vm.x), o0);
      o0 = __hfma2(W22, u2h(Vp.x), o0);
      __half2 o1 = __hmul2(WC, u2h(Vc.y));
      o1 = __hfma2(W10, u2h(SR0), o1);
      o1 = __hfma2(W12, u2h(SR1), o1);
      o1 = __hfma2(W20, u2h(Vm.y), o1);
      o1 = __hfma2(W22, u2h(Vp.y), o1);
      // leaky relu: x>=0 ? x : a*x — per-half sign-bit bit-select
      {
        unsigned u0 = h2u(o0), ua0 = h2u(__hmul2(AL, o0));
        unsigned m0 = ((u0 & 0x80008000u) >> 15) * 0xFFFFu;
        o0 = u2h((u0 & ~m0) | (ua0 & m0));
        unsigned u1 = h2u(o1), ua1 = h2u(__hmul2(AL, o1));
        unsigned m1 = ((u1 & 0x80008000u) >> 15) * 0xFFFFu;
        o1 = u2h((u1 & ~m1) | (ua1 & m1));
      }
      if (edge) {
        o0 = __hmul2(o0, CM0);
        o1 = __hmul2(o1, CM1);
        if ((unsigned)(gi0 + r) >= (unsigned)NROWS) {  // row zero
          o0 = __float2half2_rn(0.f);
          o1 = __float2half2_rn(0.f);
        }
      }
      uint2 res = {h2u(o0), h2u(o1)};
      *(uint2*)&dst[r * SSTRH + doff] = res;
      Vm = Vc; Vc = Vp;
    }
    __syncthreads();
  }

  // ---- epilogue: masked dot over interior rows [10,40), cols [10,246) ----
  const unsigned* fin = buf[0];  // pass 9 wrote buf[0]
  int i = tid >> 4;   // 0..31 (30 used)
  int part = tid & 15;
  int gi = gi0 + 10 + i;  // = by*30 + i
  float a0 = 0.f, a1 = 0.f, a2 = 0.f, a3 = 0.f;
  if (i < OHH && gi < NROWS) {
    for (int g = part; g < 59; g += 16) {
      int jc = 10 + 4 * g;
      int gj = gj0 + jc;  // = bx*236 + 4g, multiple of 4, >= 0
      if (gj + 3 < NROWS) {
        unsigned d0 = fin[(10 + i) * SSTRH + (jc >> 1)];
        unsigned d1 = fin[(10 + i) * SSTRH + (jc >> 1) + 1];
        __half2 h0 = u2h(d0), h1 = u2h(d1);
        float4 av = *(const float4*)(attn + (size_t)gi * NROWS + gj);
        const float4* op = (const float4*)opk;
        if (__low2float(h0) > 0.f)  { float4 o = op[gj + 0]; a0 += av.x * o.x; a1 += av.x * o.y; a2 += av.x * o.z; a3 += av.x * o.w; }
        if (__high2float(h0) > 0.f) { float4 o = op[gj + 1]; a0 += av.y * o.x; a1 += av.y * o.y; a2 += av.y * o.z; a3 += av.y * o.w; }
        if (__low2float(h1) > 0.f)  { float4 o = op[gj + 2]; a0 += av.z * o.x; a1 += av.z * o.y; a2 += av.z * o.z; a3 += av.z * o.w; }
        if (__high2float(h1) > 0.f) { float4 o = op[gj + 3]; a0 += av.w * o.x; a1 += av.w * o.y; a2 += av.w * o.z; a3 += av.w * o.w; }
      }
    }
  }
#pragma unroll
  for (int off = 1; off < 16; off <<= 1) {
    a0 += __shfl_xor(a0, off, 64);
    a1 += __shfl_xor(a1, off, 64);
    a2 += __shfl_xor(a2, off, 64);
    a3 += __shfl_xor(a3, off, 64);
  }
  if (part == 0 && i < OHH && gi < NROWS) {
    float4 r = {a0, a1, a2, a3};
    *(float4*)&partial[((size_t)bx * NROWS + gi) * 4] = r;
  }
}

// ---------------- kernel 4: reduce 18 partials + gcn + mlp head -----------
__global__ __launch_bounds__(64) void k_head(
    const float* __restrict__ partial, const float* __restrict__ gcn_w,
    const float* __restrict__ gcn_b, const float* __restrict__ gcn_a,
    const float* __restrict__ w1, const float* __restrict__ b1,
    const float* __restrict__ w2, const float* __restrict__ b2,
    float* __restrict__ out) {
  int row = blockIdx.x;
  int t = threadIdx.x;  // 64
  __shared__ float c4[4];
  __shared__ float gs[64];
  __shared__ float ms[32];
  {
    int c = t & 3, gg = t >> 2;  // gg in [0,16)
    float s = partial[((size_t)gg * NROWS + row) * 4 + c];
    if (gg < GX - 16)
      s += partial[((size_t)(gg + 16) * NROWS + row) * 4 + c];
#pragma unroll
    for (int off = 4; off < 64; off <<= 1) s += __shfl_xor(s, off, 64);
    if (t < 4) c4[t] = s;
  }
  __syncthreads();
  float g = gcn_b[t];
#pragma unroll
  for (int d = 0; d < 4; ++d) g += c4[d] * gcn_w[d * 64 + t];
  float ga = gcn_a[0];
  gs[t] = (g >= 0.f) ? g : ga * g;
  __syncthreads();
  if (t < 32) {
    float mm = b1[t];
#pragma unroll
    for (int i = 0; i < 64; ++i) mm += gs[i] * w1[i * 32 + t];
    ms[t] = fmaxf(mm, 0.f);
  }
  __syncthreads();
  if (t < 4) {
    float o = b2[t];
#pragma unroll
    for (int i = 0; i < 32; ++i) o += ms[i] * w2[i * 4 + t];
    out[row * 4 + t] = o;
  }
}

extern "C" void kernel_launch(void* const* d_in, const int* in_sizes, int n_in,
                              void* d_out, int out_size, void* d_ws, size_t ws_size,
                              hipStream_t stream) {
  (void)in_sizes; (void)n_in; (void)out_size; (void)ws_size;
  const float* inp    = (const float*)d_in[0];
  const float* emb_w  = (const float*)d_in[1];
  const float* emb_b  = (const float*)d_in[2];
  const float* q_w    = (const float*)d_in[3];
  const float* q_b    = (const float*)d_in[4];
  const float* k_w    = (const float*)d_in[5];
  const float* k_b    = (const float*)d_in[6];
  const float* conv_w1 = (const float*)d_in[7];
  const float* conv_w2 = (const float*)d_in[8];
  const float* conv_a  = (const float*)d_in[9];
  const float* gcn_w  = (const float*)d_in[10];
  const float* gcn_b  = (const float*)d_in[11];
  const float* gcn_a  = (const float*)d_in[12];
  const float* mlp_w1 = (const float*)d_in[13];
  const float* mlp_b1 = (const float*)d_in[14];
  const float* mlp_w2 = (const float*)d_in[15];
  const float* mlp_b2 = (const float*)d_in[16];
  float* out = (float*)d_out;

  const size_t NN = (size_t)NROWS * NROWS;
  float* A       = (float*)d_ws;                      // 4096^2 attn
  float* partial = A + NN;                            // GX * 4096 * 4
  float* q       = partial + (size_t)GX * NROWS * 4;
  float* kT      = q + (size_t)NROWS * HID;
  float* opk     = kT + (size_t)NROWS * HID;          // 4096*4

  k_embed<<<NROWS, 64, 0, stream>>>(inp, emb_w, emb_b, q_w, q_b, k_w, k_b, q, kT, opk);
  k_scores<<<NROWS / 8, 512, 0, stream>>>(q, kT, A);
  k_conv3<<<dim3(GX, GY), 512, 0, stream>>>(A, partial, conv_w1, conv_w2,
                                            conv_a, opk);
  k_head<<<NROWS, 64, 0, stream>>>(partial, gcn_w, gcn_b, gcn_a, mlp_w1, mlp_b1,
                                   mlp_w2, mlp_b2, out);
}